// Round 2
// baseline (4169.529 us; speedup 1.0000x reference)
//
#include <hip/hip_runtime.h>
#include <math.h>

#define BATCH 8
#define SEQ   2048
#define DIM   512
#define BM    64    // Q rows per block
#define BN    128   // KV cols per s-tile
#define DC    64    // d-chunk for QK staging
#define DV    128   // d-chunk for PV staging
#define NTH   512

__global__ __launch_bounds__(NTH, 2)
void attn_fp32_kernel(const float* __restrict__ Q, const float* __restrict__ K,
                      const float* __restrict__ V, const int* __restrict__ mfp,
                      float* __restrict__ Out)
{
    const int tid = threadIdx.x;
    const int mg  = tid >> 5;    // 0..15 -> rows 4*mg..4*mg+3
    const int ng  = tid & 31;    // 0..31 -> QK cols 4*ng..+3 ; PV d-cols 4*ng..+3
    const int b   = blockIdx.x >> 5;          // SEQ/BM = 32 tiles per batch
    const int m0  = (blockIdx.x & 31) * BM;
    const int mf  = mfp[0];

    // LDS overlays: Qs and Vs never live simultaneously; Ks and Ps never live
    // simultaneously (barriers below enforce the phase separation).
    __shared__ union { float q[BM][DC + 4]; float v[BN][DV + 4]; } QV;
    __shared__ union { float k[BN][DC];     float p[BM][BN + 4]; } KP;

    const float dk = 22.627416997969522f;   // sqrt(512) in fp32

    float o[4][4][4];      // [row i][dv chunk][col j]
    float m_run[4], l_run[4];
    #pragma unroll
    for (int i = 0; i < 4; i++) {
        m_run[i] = -INFINITY; l_run[i] = 0.f;
        #pragma unroll
        for (int dv = 0; dv < 4; dv++)
            #pragma unroll
            for (int j = 0; j < 4; j++) o[i][dv][j] = 0.f;
    }

    const float* Qb = Q + (size_t)b * SEQ * DIM;
    const float* Kb = K + (size_t)b * SEQ * DIM;
    const float* Vb = V + (size_t)b * SEQ * DIM;

    for (int s0 = 0; s0 < SEQ; s0 += BN) {
        // ---------------- S = Q*K^T (fp32, d-chunked) ----------------
        float sacc[4][4];
        #pragma unroll
        for (int i = 0; i < 4; i++)
            #pragma unroll
            for (int j = 0; j < 4; j++) sacc[i][j] = 0.f;

        for (int dc = 0; dc < DIM; dc += DC) {
            __syncthreads();   // (A) protect Qs/Ks overwrite vs all prior readers
            {   // load Q chunk [64][64]: 16 lanes/row, 256B contiguous per row
                const int r  = tid >> 4;
                const int c4 = tid & 15;
                #pragma unroll
                for (int p = 0; p < 2; p++) {
                    const int row = p * 32 + r;
                    float4 t = *(const float4*)(Qb + (m0 + row) * DIM + dc + c4 * 4);
                    *(float4*)&QV.q[row][c4 * 4] = t;
                }
            }
            {   // load K chunk [128][64] with 16B-chunk XOR swizzle
                const int r  = tid >> 4;
                const int c4 = tid & 15;
                #pragma unroll
                for (int p = 0; p < 4; p++) {
                    const int row = p * 32 + r;
                    float4 t = *(const float4*)(Kb + (s0 + row) * DIM + dc + c4 * 4);
                    const int cs = c4 ^ ((row >> 2) & 15);
                    *(float4*)&KP.k[row][cs * 4] = t;
                }
            }
            __syncthreads();   // (B) staged data visible

            #pragma unroll
            for (int dd4 = 0; dd4 < 16; dd4++) {
                float4 q[4], k[4];
                #pragma unroll
                for (int i = 0; i < 4; i++)
                    q[i] = *(const float4*)&QV.q[4 * mg + i][dd4 * 4];
                const int cs = dd4 ^ (ng & 15);   // (n>>2)&15 == ng&15 for n=4ng+j
                #pragma unroll
                for (int j = 0; j < 4; j++)
                    k[j] = *(const float4*)&KP.k[4 * ng + j][cs * 4];
                #pragma unroll
                for (int i = 0; i < 4; i++)
                    #pragma unroll
                    for (int j = 0; j < 4; j++)
                        sacc[i][j] += q[i].x * k[j].x + q[i].y * k[j].y
                                    + q[i].z * k[j].z + q[i].w * k[j].w;
            }
        }

        // ---------------- mask * scale, online softmax ----------------
        float pvals[4][4];
        float fscale[4];
        #pragma unroll
        for (int i = 0; i < 4; i++) {
            const int tg = m0 + 4 * mg + i;
            float z[4];
            float rmax = -INFINITY;
            #pragma unroll
            for (int j = 0; j < 4; j++) {
                const int sg = s0 + 4 * ng + j;
                const float mult = (mf && sg >= tg) ? -1e9f : 1.0f;
                z[j] = sacc[i][j] * mult / dk;
                rmax = fmaxf(rmax, z[j]);
            }
            #pragma unroll
            for (int off = 1; off < 32; off <<= 1)
                rmax = fmaxf(rmax, __shfl_xor(rmax, off, 32));
            const float mnew = fmaxf(m_run[i], rmax);
            float psum = 0.f;
            #pragma unroll
            for (int j = 0; j < 4; j++) {
                const float p = expf(z[j] - mnew);
                pvals[i][j] = p;
                psum += p;
            }
            #pragma unroll
            for (int off = 1; off < 32; off <<= 1)
                psum += __shfl_xor(psum, off, 32);
            const float f = expf(m_run[i] - mnew);   // -inf first tile -> 0
            fscale[i] = f;
            l_run[i]  = l_run[i] * f + psum;
            m_run[i]  = mnew;
        }

        __syncthreads();   // (C) last Ks reads done before Ps overwrites (overlay!)
        #pragma unroll
        for (int i = 0; i < 4; i++)
            *(float4*)&KP.p[4 * mg + i][4 * ng] =
                make_float4(pvals[i][0], pvals[i][1], pvals[i][2], pvals[i][3]);

        #pragma unroll
        for (int i = 0; i < 4; i++)
            #pragma unroll
            for (int dv = 0; dv < 4; dv++)
                #pragma unroll
                for (int j = 0; j < 4; j++) o[i][dv][j] *= fscale[i];

        // ---------------- O += P*V (d-chunked) ----------------
        #pragma unroll
        for (int dv = 0; dv < 4; dv++) {
            __syncthreads();   // (D) Ps visible (dv0); prev Vs reads done
            {   // load V chunk [128][128]: 32 lanes/row, 512B contiguous
                const int r = tid >> 5;
                const int c = tid & 31;
                #pragma unroll
                for (int p = 0; p < 8; p++) {
                    const int row = p * 16 + r;
                    float4 t = *(const float4*)(Vb + (s0 + row) * DIM + dv * DV + c * 4);
                    *(float4*)&QV.v[row][c * 4] = t;
                }
            }
            __syncthreads();   // (E)

            #pragma unroll
            for (int n4 = 0; n4 < 32; n4++) {
                float parr[4][4];
                #pragma unroll
                for (int i = 0; i < 4; i++) {
                    float4 t = *(const float4*)&KP.p[4 * mg + i][n4 * 4];
                    parr[i][0] = t.x; parr[i][1] = t.y; parr[i][2] = t.z; parr[i][3] = t.w;
                }
                #pragma unroll
                for (int jj = 0; jj < 4; jj++) {
                    const float4 vv = *(const float4*)&QV.v[n4 * 4 + jj][4 * ng];
                    #pragma unroll
                    for (int i = 0; i < 4; i++) {
                        const float p = parr[i][jj];
                        o[i][dv][0] += p * vv.x;
                        o[i][dv][1] += p * vv.y;
                        o[i][dv][2] += p * vv.z;
                        o[i][dv][3] += p * vv.w;
                    }
                }
            }
        }
    }

    // ---------------- epilogue: O / l ----------------
    #pragma unroll
    for (int i = 0; i < 4; i++) {
        const float il = 1.0f / l_run[i];
        const int row = m0 + 4 * mg + i;
        #pragma unroll
        for (int dv = 0; dv < 4; dv++) {
            float4 r;
            r.x = o[i][dv][0] * il;
            r.y = o[i][dv][1] * il;
            r.z = o[i][dv][2] * il;
            r.w = o[i][dv][3] * il;
            *(float4*)(Out + ((size_t)b * SEQ + row) * DIM + dv * DV + 4 * ng) = r;
        }
    }
}

extern "C" void kernel_launch(void* const* d_in, const int* in_sizes, int n_in,
                              void* d_out, int out_size, void* d_ws, size_t ws_size,
                              hipStream_t stream) {
    const float* Q  = (const float*)d_in[0];
    const float* K  = (const float*)d_in[1];
    const float* V  = (const float*)d_in[2];
    const int*   mf = (const int*)d_in[3];
    float* O = (float*)d_out;

    dim3 grid(BATCH * (SEQ / BM));   // 256 blocks, 1 per CU
    dim3 block(NTH);
    attn_fp32_kernel<<<grid, block, 0, stream>>>(Q, K, V, mf, O);
}

// Round 6
// 1296.627 us; speedup vs baseline: 3.2157x; 3.2157x over previous
//
#include <hip/hip_runtime.h>
#include <math.h>

#define BATCH 8
#define SEQ   2048
#define DIM   512
#define NTH   256

typedef unsigned int u32;
typedef _Float16 h2  __attribute__((ext_vector_type(2)));
typedef _Float16 h8  __attribute__((ext_vector_type(8)));
typedef float    f4  __attribute__((ext_vector_type(4)));
typedef u32      u4v __attribute__((ext_vector_type(4)));

#define MFMA16(a,b,c) __builtin_amdgcn_mfma_f32_16x16x32_f16((a),(b),(c),0,0,0)

__device__ __forceinline__ u32 pack2(float a, float b) {
    h2 t; t[0] = (_Float16)a; t[1] = (_Float16)b;
    return __builtin_bit_cast(u32, t);
}

// Block: 64 Q-rows × full D; s-tiles of 128. 256 threads = 4 waves.
// QK on fp32 VALU (R1-proven numerics), PV on f16 MFMA (NaN-impossible inputs).
__global__ __launch_bounds__(NTH, 1)
void attn_kernel(const float* __restrict__ Q, const float* __restrict__ K,
                 const float* __restrict__ V, const int* __restrict__ mfp,
                 float* __restrict__ Out)
{
    __shared__ float Qs[64][68];    // Q d-chunk (64), pad 4   -> 17 KiB
    __shared__ float Ks[128][64];   // K d-chunk, XOR-swizzled -> 32 KiB
    __shared__ u32   Pp[64][68];    // P as packed f16 pairs   -> 17 KiB
    __shared__ u32   Vp[64][68];    // V d-chunk packed pairs  -> 17 KiB

    const int tid = threadIdx.x;
    const int w   = tid >> 6;        // wave 0..3
    const int lx  = (tid & 63) & 15; // lane & 15
    const int lg  = (tid & 63) >> 4; // lane group 0..3
    const int ty  = tid >> 4;        // 0..15 : Q rows 4ty..4ty+3   (ty = 4w+lg)
    const int tx  = tid & 15;        // 0..15 : K cols 8tx..8tx+7   (tx = lx)
    const int b   = blockIdx.x >> 5;
    const int m0  = (blockIdx.x & 31) * 64;
    const int mf  = mfp[0];

    const float* __restrict__ Qb = Q + (size_t)b * SEQ * DIM;
    const float* __restrict__ Kb = K + (size_t)b * SEQ * DIM;
    const float* __restrict__ Vb = V + (size_t)b * SEQ * DIM;

    // staging maps
    const int qsr = tid >> 2, qsc = tid & 3;   // Q: row, 16-col quarter
    const int ksr = tid >> 1, ksc = tid & 1;   // K: row, 32-col half
    const int vsp = tid >> 2, vsc = tid & 3;   // V: s-pair, 16-col quarter

    f4 o[32];                         // PV accum, MFMA C/D layout
    const f4 fz = {0.f, 0.f, 0.f, 0.f};
    #pragma unroll
    for (int i = 0; i < 32; i++) o[i] = fz;
    float m_run[4] = {-INFINITY, -INFINITY, -INFINITY, -INFINITY};
    float l_run[4] = {0.f, 0.f, 0.f, 0.f};

    const float dk = 22.627416997969522f;   // sqrt(512)

    for (int s0 = 0; s0 < SEQ; s0 += 128) {
        // ================= S = Q K^T : fp32 VALU, 4x8 per thread =================
        float sacc[4][8];
        #pragma unroll
        for (int i = 0; i < 4; i++)
            #pragma unroll
            for (int j = 0; j < 8; j++) sacc[i][j] = 0.f;

        float4 qreg[4], kreg[8];
        #pragma unroll
        for (int c = 0; c < 4; c++)
            qreg[c] = *(const float4*)(Qb + (size_t)(m0 + qsr) * DIM + 16 * qsc + 4 * c);
        #pragma unroll
        for (int c = 0; c < 8; c++)
            kreg[c] = *(const float4*)(Kb + (size_t)(s0 + ksr) * DIM + 32 * ksc + 4 * c);

        for (int dc = 0; dc < 8; dc++) {
            __syncthreads();   // prior readers of Qs/Ks done
            #pragma unroll
            for (int c = 0; c < 4; c++)
                *(float4*)&Qs[qsr][16 * qsc + 4 * c] = qreg[c];
            #pragma unroll
            for (int c = 0; c < 8; c++) {
                const int ch  = 8 * ksc + c;                    // 16B chunk 0..15
                const int chs = ch ^ ((ksr >> 3) & 7);          // XOR swizzle
                *(float4*)&Ks[ksr][4 * chs] = kreg[c];
            }
            __syncthreads();   // staged chunk visible
            if (dc < 7) {      // register prefetch of next d-chunk
                #pragma unroll
                for (int c = 0; c < 4; c++)
                    qreg[c] = *(const float4*)(Qb + (size_t)(m0 + qsr) * DIM
                                               + (dc + 1) * 64 + 16 * qsc + 4 * c);
                #pragma unroll
                for (int c = 0; c < 8; c++)
                    kreg[c] = *(const float4*)(Kb + (size_t)(s0 + ksr) * DIM
                                               + (dc + 1) * 64 + 32 * ksc + 4 * c);
            }
            #pragma unroll 2
            for (int kk = 0; kk < 16; kk++) {
                float4 q4[4], k4[8];
                #pragma unroll
                for (int i = 0; i < 4; i++)
                    q4[i] = *(const float4*)&Qs[4 * ty + i][4 * kk];   // broadcast
                #pragma unroll
                for (int j = 0; j < 8; j++)
                    k4[j] = *(const float4*)&Ks[8 * tx + j][4 * (kk ^ (tx & 7))];
                #pragma unroll
                for (int i = 0; i < 4; i++)
                    #pragma unroll
                    for (int j = 0; j < 8; j++)
                        sacc[i][j] += q4[i].x * k4[j].x + q4[i].y * k4[j].y
                                    + q4[i].z * k4[j].z + q4[i].w * k4[j].w;
            }
        }

        // Insurance: legit |scores| <= ~150. Clamp keeps garbage finite through
        // the -1e9 mask multiply (2e4*1e9*inv_dk ~ 8.8e11 << FLT_MAX): no NaN.
        #pragma unroll
        for (int i = 0; i < 4; i++)
            #pragma unroll
            for (int j = 0; j < 8; j++)
                sacc[i][j] = fminf(fmaxf(sacc[i][j], -2.0e4f), 2.0e4f);

        // ============ mask*scale + online softmax (R1-verbatim math) ============
        float pw[4][8];
        float fscale[4];
        #pragma unroll
        for (int r = 0; r < 4; r++) {
            const int tg = m0 + 4 * ty + r;
            float z[8];
            float zm = -INFINITY;
            #pragma unroll
            for (int j = 0; j < 8; j++) {
                const int sg = s0 + 8 * tx + j;
                const float mult = (mf && sg >= tg) ? -1.0e9f : 1.0f;
                z[j] = sacc[r][j] * mult / dk;
                zm = fmaxf(zm, z[j]);
            }
            #pragma unroll
            for (int mm = 1; mm < 16; mm <<= 1) zm = fmaxf(zm, __shfl_xor(zm, mm));
            const float mnew = fmaxf(m_run[r], zm);
            float ps = 0.f;
            #pragma unroll
            for (int j = 0; j < 8; j++) {
                const float p = expf(z[j] - mnew);
                pw[r][j] = p;
                ps += p;
            }
            #pragma unroll
            for (int mm = 1; mm < 16; mm <<= 1) ps += __shfl_xor(ps, mm);
            const float fs = expf(m_run[r] - mnew);   // first tile: exp(-inf)=0
            fscale[r] = fs;
            l_run[r]  = l_run[r] * fs + ps;
            m_run[r]  = mnew;
        }

        // P -> LDS as packed f16 pairs: Pp[row][sc] = {P[row][2sc], P[row][2sc+1]}
        #pragma unroll
        for (int r = 0; r < 4; r++)
            #pragma unroll
            for (int mpair = 0; mpair < 4; mpair++)
                Pp[4 * ty + r][4 * tx + mpair] =
                    pack2(pw[r][2 * mpair], pw[r][2 * mpair + 1]);

        // rescale accumulators (o rows = 4*ty + rr, lane-local match with fscale)
        #pragma unroll
        for (int i = 0; i < 32; i++) {
            f4 t = o[i];
            t[0] *= fscale[0]; t[1] *= fscale[1]; t[2] *= fscale[2]; t[3] *= fscale[3];
            o[i] = t;
        }

        // ================= O += P V : f16 MFMA, fp32 accum =================
        float4 va[4], vb[4];   // two V rows (s-pair), 16 cols each
        #pragma unroll
        for (int c = 0; c < 4; c++) {
            va[c] = *(const float4*)(Vb + (size_t)(s0 + 2 * vsp)     * DIM + 16 * vsc + 4 * c);
            vb[c] = *(const float4*)(Vb + (size_t)(s0 + 2 * vsp + 1) * DIM + 16 * vsc + 4 * c);
        }

        h8 pa[4];
        #pragma unroll
        for (int dv = 0; dv < 8; dv++) {
            __syncthreads();   // prior readers of Vp done
            #pragma unroll
            for (int c = 0; c < 4; c++) {
                #pragma unroll
                for (int e = 0; e < 4; e++) {
                    const float x0 = (e == 0) ? va[c].x : (e == 1) ? va[c].y : (e == 2) ? va[c].z : va[c].w;
                    const float x1 = (e == 0) ? vb[c].x : (e == 1) ? vb[c].y : (e == 2) ? vb[c].z : vb[c].w;
                    Vp[vsp][16 * vsc + 4 * c + e] = pack2(x0, x1);
                }
            }
            __syncthreads();   // staged V chunk (and, for dv=0, Pp) visible
            if (dv < 7) {
                #pragma unroll
                for (int c = 0; c < 4; c++) {
                    va[c] = *(const float4*)(Vb + (size_t)(s0 + 2 * vsp)     * DIM
                                             + (dv + 1) * 64 + 16 * vsc + 4 * c);
                    vb[c] = *(const float4*)(Vb + (size_t)(s0 + 2 * vsp + 1) * DIM
                                             + (dv + 1) * 64 + 16 * vsc + 4 * c);
                }
            }
            if (dv == 0) {
                // A-frag: row = lane&15 (m = w*16+lx), slot e <-> s = 32*ks4+8*lg+e
                #pragma unroll
                for (int ks4 = 0; ks4 < 4; ks4++)
                    pa[ks4] = __builtin_bit_cast(h8,
                        *(const u4v*)&Pp[w * 16 + lx][16 * ks4 + 4 * lg]);
            }
            #pragma unroll
            for (int ks4 = 0; ks4 < 4; ks4++) {
                #pragma unroll
                for (int dt = 0; dt < 4; dt++) {
                    const int dcol = dt * 16 + lx;
                    // B-frag: col = lane&15, slot e <-> s = 32*ks4+8*lg+e
                    u4v uv;
                    uv[0] = Vp[16 * ks4 + 4 * lg + 0][dcol];
                    uv[1] = Vp[16 * ks4 + 4 * lg + 1][dcol];
                    uv[2] = Vp[16 * ks4 + 4 * lg + 2][dcol];
                    uv[3] = Vp[16 * ks4 + 4 * lg + 3][dcol];
                    const h8 vfrag = __builtin_bit_cast(h8, uv);
                    o[dv * 4 + dt] = MFMA16(pa[ks4], vfrag, o[dv * 4 + dt]);
                }
            }
        }
    }

    // ================= epilogue: O / l =================
    float il[4];
    #pragma unroll
    for (int r = 0; r < 4; r++) il[r] = 1.0f / l_run[r];
    #pragma unroll
    for (int dv = 0; dv < 8; dv++)
        #pragma unroll
        for (int dt = 0; dt < 4; dt++) {
            const f4 ov = o[dv * 4 + dt];
            #pragma unroll
            for (int rr = 0; rr < 4; rr++) {
                const size_t row = (size_t)b * SEQ + m0 + 4 * ty + rr;
                Out[row * DIM + dv * 64 + dt * 16 + lx] = ov[rr] * il[rr];
            }
        }
}

extern "C" void kernel_launch(void* const* d_in, const int* in_sizes, int n_in,
                              void* d_out, int out_size, void* d_ws, size_t ws_size,
                              hipStream_t stream) {
    const float* Q  = (const float*)d_in[0];
    const float* K  = (const float*)d_in[1];
    const float* V  = (const float*)d_in[2];
    const int*   mf = (const int*)d_in[3];
    float* O = (float*)d_out;

    dim3 grid(BATCH * (SEQ / 64));   // 256 blocks, 1 per CU
    dim3 block(NTH);
    attn_kernel<<<grid, block, 0, stream>>>(Q, K, V, mf, O);
}

// Round 7
// 450.916 us; speedup vs baseline: 9.2468x; 2.8755x over previous
//
#include <hip/hip_runtime.h>
#include <math.h>

#define BATCH 8
#define SEQ   2048
#define DIM   512
#define NTH   256

typedef unsigned int u32;
typedef _Float16 h2  __attribute__((ext_vector_type(2)));
typedef _Float16 h8  __attribute__((ext_vector_type(8)));
typedef float    f4  __attribute__((ext_vector_type(4)));
typedef u32      u4v __attribute__((ext_vector_type(4)));

#define MFMA16(a,b,c) __builtin_amdgcn_mfma_f32_16x16x32_f16((a),(b),(c),0,0,0)

__device__ __forceinline__ u32 pack2(float a, float b) {
    h2 t; t[0] = (_Float16)a; t[1] = (_Float16)b;
    return __builtin_bit_cast(u32, t);
}
__device__ __forceinline__ void split2(float a, float b, u32& hi, u32& lo) {
    _Float16 ha = (_Float16)a, hb = (_Float16)b;
    _Float16 la = (_Float16)(a - (float)ha), lb = (_Float16)(b - (float)hb);
    h2 th; th[0] = ha; th[1] = hb; hi = __builtin_bit_cast(u32, th);
    h2 tl; tl[0] = la; tl[1] = lb; lo = __builtin_bit_cast(u32, tl);
}

// R5-minimal-delta: QK moves to f16 hi/lo MFMA; softmax/P-pack/PV/epilogue keep
// R5's validated maps. All MFMA fragment maps identical to R5's passing PV path:
//   A: row=lane&15, k-slot e <-> k = 8*((lane>>4)&3) + e   (per 32-k window)
//   B: col=lane&15, same k-slot map
//   C/D: row = 4*((lane>>4)&3) + reg, col = lane&15
__global__ __launch_bounds__(NTH, 1)
void attn_kernel(const float* __restrict__ Q, const float* __restrict__ K,
                 const float* __restrict__ V, const int* __restrict__ mfp,
                 float* __restrict__ Out)
{
    __shared__ u32 Kth[32][132];   // K^T hi pairs: [d-pair 0..31][s 0..127]
    __shared__ u32 Ktl[32][132];   // K^T lo pairs
    __shared__ u32 Pp [64][68];    // P packed s-pairs (R5-verbatim layout)
    __shared__ u32 Vp [64][68];    // V packed s-pair rows (R5-verbatim layout)

    const int tid = threadIdx.x;
    const int w   = tid >> 6;          // wave 0..3 -> Q rows 16w..16w+15
    const int lx  = tid & 15;          // lane & 15
    const int lg  = (tid >> 4) & 3;    // lane group 0..3
    const int b   = blockIdx.x >> 5;
    const int m0  = (blockIdx.x & 31) * 64;
    const int mf  = mfp[0];

    const int ksr = tid >> 1, ksc = tid & 1;   // K staging: row 0..127, d-half
    const int vsp = tid >> 2, vsc = tid & 3;   // V staging (R5-verbatim)

    const float* __restrict__ Qb = Q + (size_t)b * SEQ * DIM;
    const float* __restrict__ Kb = K + (size_t)b * SEQ * DIM;
    const float* __restrict__ Vb = V + (size_t)b * SEQ * DIM;

    // ---- Q fragments in registers, hi/lo split, built via pack2/u4v forms ----
    h8 qh[16], ql[16];
    {
        const float* qrowp = Qb + (size_t)(m0 + w * 16 + lx) * DIM;
        #pragma unroll
        for (int t = 0; t < 16; t++) {
            float bufv[8];
            *(float4*)&bufv[0] = *(const float4*)(qrowp + 32 * t + 8 * lg);
            *(float4*)&bufv[4] = *(const float4*)(qrowp + 32 * t + 8 * lg + 4);
            u4v uh, ul;
            #pragma unroll
            for (int i = 0; i < 4; i++) {
                u32 hi, lo;
                split2(bufv[2 * i], bufv[2 * i + 1], hi, lo);
                uh[i] = hi; ul[i] = lo;
            }
            qh[t] = __builtin_bit_cast(h8, uh);
            ql[t] = __builtin_bit_cast(h8, ul);
        }
    }

    f4 o[32];
    const f4 fz = {0.f, 0.f, 0.f, 0.f};
    #pragma unroll
    for (int i = 0; i < 32; i++) o[i] = fz;
    float m_run[4] = {-INFINITY, -INFINITY, -INFINITY, -INFINITY};
    float l_run[4] = {0.f, 0.f, 0.f, 0.f};

    const float dk = 22.627416997969522f;   // sqrt(512)

    for (int s0 = 0; s0 < SEQ; s0 += 128) {
        // ============ S = Q K^T : f16 hi/lo MFMA, fp32 accum ============
        f4 sa[8];   // col-tiles nt: cols nt*16+lx; rows 4lg+r
        #pragma unroll
        for (int nt = 0; nt < 8; nt++) sa[nt] = fz;

        float4 kreg[8];
        #pragma unroll
        for (int c = 0; c < 8; c++)
            kreg[c] = *(const float4*)(Kb + (size_t)(s0 + ksr) * DIM + 32 * ksc + 4 * c);

        #pragma unroll
        for (int dc = 0; dc < 8; dc++) {
            __syncthreads();   // prior readers of Kth/Ktl done
            #pragma unroll
            for (int c = 0; c < 8; c++) {
                u32 hi0, lo0, hi1, lo1;
                split2(kreg[c].x, kreg[c].y, hi0, lo0);
                split2(kreg[c].z, kreg[c].w, hi1, lo1);
                const int dp = 16 * ksc + 2 * c;     // d-pair row in chunk
                Kth[dp][ksr]     = hi0;   // bank (4dp+s)%32: s spans all -> clean
                Kth[dp + 1][ksr] = hi1;
                Ktl[dp][ksr]     = lo0;
                Ktl[dp + 1][ksr] = lo1;
            }
            __syncthreads();   // staged transposed chunk visible
            if (dc < 7) {      // register prefetch of next d-chunk
                #pragma unroll
                for (int c = 0; c < 8; c++)
                    kreg[c] = *(const float4*)(Kb + (size_t)(s0 + ksr) * DIM
                                               + (dc + 1) * 64 + 32 * ksc + 4 * c);
            }
            #pragma unroll
            for (int tl = 0; tl < 2; tl++) {
                const int t = 2 * dc + tl;
                #pragma unroll
                for (int nt = 0; nt < 8; nt++) {
                    const int scol = nt * 16 + lx;
                    u4v uh, ul;
                    #pragma unroll
                    for (int i = 0; i < 4; i++) {
                        uh[i] = Kth[16 * tl + 4 * lg + i][scol];  // 2-way banks: free
                        ul[i] = Ktl[16 * tl + 4 * lg + i][scol];
                    }
                    const h8 kh = __builtin_bit_cast(h8, uh);
                    const h8 kl = __builtin_bit_cast(h8, ul);
                    sa[nt] = MFMA16(qh[t], kh, sa[nt]);
                    sa[nt] = MFMA16(qh[t], kl, sa[nt]);
                    sa[nt] = MFMA16(ql[t], kh, sa[nt]);
                }
            }
        }

        // NaN-scrub + clamp: any garbage becomes finite-wrong (diagnosable), never NaN.
        #pragma unroll
        for (int nt = 0; nt < 8; nt++)
            #pragma unroll
            for (int r = 0; r < 4; r++) {
                float s = sa[nt][r];
                s = (s == s) ? s : 0.0f;
                sa[nt][r] = fminf(fmaxf(s, -2.0e4f), 2.0e4f);
            }

        // ============ mask*scale + online softmax (R5-verbatim math) ============
        float pw[4][8];
        float fscale[4];
        #pragma unroll
        for (int r = 0; r < 4; r++) {
            const int tg = m0 + w * 16 + 4 * lg + r;
            float z[8];
            float zm = -INFINITY;
            #pragma unroll
            for (int nt = 0; nt < 8; nt++) {
                const int sg = s0 + nt * 16 + lx;
                const float mult = (mf && sg >= tg) ? -1.0e9f : 1.0f;
                z[nt] = sa[nt][r] * mult / dk;
                zm = fmaxf(zm, z[nt]);
            }
            #pragma unroll
            for (int mm = 1; mm < 16; mm <<= 1) zm = fmaxf(zm, __shfl_xor(zm, mm));
            const float mnew = fmaxf(m_run[r], zm);
            float ps = 0.f;
            #pragma unroll
            for (int nt = 0; nt < 8; nt++) {
                const float p = expf(z[nt] - mnew);
                pw[r][nt] = p;
                ps += p;
            }
            #pragma unroll
            for (int mm = 1; mm < 16; mm <<= 1) ps += __shfl_xor(ps, mm);
            const float fs = expf(m_run[r] - mnew);   // first tile: exp(-inf)=0
            fscale[r] = fs;
            l_run[r]  = l_run[r] * fs + ps;
            m_run[r]  = mnew;
        }

        // P -> Pp packed s-pairs (R5 layout). Adjacent s live in adjacent lanes:
        // pair via shfl, even lanes store. Pp rows are wave-private.
        #pragma unroll
        for (int r = 0; r < 4; r++)
            #pragma unroll
            for (int nt = 0; nt < 8; nt++) {
                const float self = pw[r][nt];
                const float nb   = __shfl_xor(self, 1);
                if (!(lx & 1))
                    Pp[w * 16 + 4 * lg + r][8 * nt + (lx >> 1)] = pack2(self, nb);
            }

        // rescale accumulators (o rows = 4lg+r match fscale[r])
        #pragma unroll
        for (int i = 0; i < 32; i++) {
            f4 t = o[i];
            t[0] *= fscale[0]; t[1] *= fscale[1]; t[2] *= fscale[2]; t[3] *= fscale[3];
            o[i] = t;
        }

        // ================= O += P V : R5-verbatim =================
        float4 va[4], vb[4];
        #pragma unroll
        for (int c = 0; c < 4; c++) {
            va[c] = *(const float4*)(Vb + (size_t)(s0 + 2 * vsp)     * DIM + 16 * vsc + 4 * c);
            vb[c] = *(const float4*)(Vb + (size_t)(s0 + 2 * vsp + 1) * DIM + 16 * vsc + 4 * c);
        }

        h8 pa[4];
        #pragma unroll
        for (int dv = 0; dv < 8; dv++) {
            __syncthreads();   // prior readers of Vp done
            #pragma unroll
            for (int c = 0; c < 4; c++) {
                #pragma unroll
                for (int e = 0; e < 4; e++) {
                    const float x0 = (e == 0) ? va[c].x : (e == 1) ? va[c].y : (e == 2) ? va[c].z : va[c].w;
                    const float x1 = (e == 0) ? vb[c].x : (e == 1) ? vb[c].y : (e == 2) ? vb[c].z : vb[c].w;
                    Vp[vsp][16 * vsc + 4 * c + e] = pack2(x0, x1);
                }
            }
            __syncthreads();   // staged V chunk (and, for dv=0, Pp) visible
            if (dv < 7) {
                #pragma unroll
                for (int c = 0; c < 4; c++) {
                    va[c] = *(const float4*)(Vb + (size_t)(s0 + 2 * vsp)     * DIM
                                             + (dv + 1) * 64 + 16 * vsc + 4 * c);
                    vb[c] = *(const float4*)(Vb + (size_t)(s0 + 2 * vsp + 1) * DIM
                                             + (dv + 1) * 64 + 16 * vsc + 4 * c);
                }
            }
            if (dv == 0) {
                #pragma unroll
                for (int ks4 = 0; ks4 < 4; ks4++)
                    pa[ks4] = __builtin_bit_cast(h8,
                        *(const u4v*)&Pp[w * 16 + lx][16 * ks4 + 4 * lg]);
            }
            #pragma unroll
            for (int ks4 = 0; ks4 < 4; ks4++) {
                #pragma unroll
                for (int dt = 0; dt < 4; dt++) {
                    const int dcol = dt * 16 + lx;
                    u4v uv;
                    uv[0] = Vp[16 * ks4 + 4 * lg + 0][dcol];
                    uv[1] = Vp[16 * ks4 + 4 * lg + 1][dcol];
                    uv[2] = Vp[16 * ks4 + 4 * lg + 2][dcol];
                    uv[3] = Vp[16 * ks4 + 4 * lg + 3][dcol];
                    const h8 vfrag = __builtin_bit_cast(h8, uv);
                    o[dv * 4 + dt] = MFMA16(pa[ks4], vfrag, o[dv * 4 + dt]);
                }
            }
        }
    }

    // ================= epilogue: O / l (R5-verbatim rows) =================
    float il[4];
    #pragma unroll
    for (int r = 0; r < 4; r++) il[r] = 1.0f / l_run[r];
    #pragma unroll
    for (int dv = 0; dv < 8; dv++)
        #pragma unroll
        for (int dt = 0; dt < 4; dt++) {
            const f4 ov = o[dv * 4 + dt];
            #pragma unroll
            for (int rr = 0; rr < 4; rr++) {
                const size_t row = (size_t)b * SEQ + m0 + w * 16 + 4 * lg + rr;
                Out[row * DIM + dv * 64 + dt * 16 + lx] = ov[rr] * il[rr];
            }
        }
}

extern "C" void kernel_launch(void* const* d_in, const int* in_sizes, int n_in,
                              void* d_out, int out_size, void* d_ws, size_t ws_size,
                              hipStream_t stream) {
    const float* Q  = (const float*)d_in[0];
    const float* K  = (const float*)d_in[1];
    const float* V  = (const float*)d_in[2];
    const int*   mf = (const int*)d_in[3];
    float* O = (float*)d_out;

    dim3 grid(BATCH * (SEQ / 64));   // 256 blocks, 1 per CU
    dim3 block(NTH);
    attn_kernel<<<grid, block, 0, stream>>>(Q, K, V, mf, O);
}